// Round 9
// baseline (284.687 us; speedup 1.0000x reference)
//
#include <hip/hip_runtime.h>
#include <math.h>

#define N_NODES 100000
#define N_EDGES 1600000
#define D_IN    128
#define HIDDEN  128
#define D_OUT   64

// ---- bucketed counting sort params ----
#define BUCKET_SHIFT 8
#define NB_BUCKETS ((N_NODES + 255) / 256)   // 391
#define BUCKET_CAP 6144
#define EPT 16
#define EPB (256 * EPT)                      // 4096
#define NBLK_SCATTER ((N_EDGES + EPB - 1) / EPB)        // 391
#define NBLK_CONVERT ((N_NODES * 16 + 255) / 256)       // 6250 (2 float4/thread)
#define NBLK_PREPB   ((256 * 128 + 128 * 128 + 255) / 256)  // 192

typedef short bf16x8 __attribute__((ext_vector_type(8)));
typedef float f32x4  __attribute__((ext_vector_type(4)));
typedef float f32x2  __attribute__((ext_vector_type(2)));
typedef _Float16 h2 __attribute__((ext_vector_type(2)));

#if defined(__has_builtin)
# if __has_builtin(__builtin_amdgcn_fdot2)
#  define USE_FDOT2 1
# endif
#endif
#ifndef USE_FDOT2
# define USE_FDOT2 0
#endif

__device__ __forceinline__ unsigned short f2bf(float f) {
    union { float f; unsigned u; } v; v.f = f;
    unsigned r = v.u + 0x7FFF + ((v.u >> 16) & 1);   // RNE
    return (unsigned short)(r >> 16);
}
__device__ __forceinline__ float bf2f_lo(unsigned u) {
    union { unsigned u; float f; } v; v.u = u << 16; return v.f;
}
__device__ __forceinline__ float bf2f_hi(unsigned u) {
    union { unsigned u; float f; } v; v.u = u & 0xFFFF0000u; return v.f;
}
__device__ __forceinline__ h2 as_h2(unsigned u) {
    union { unsigned u; h2 h; } c; c.u = u; return c.h;
}
__device__ __forceinline__ unsigned short f2h_bits(float f) {
    union { _Float16 h; unsigned short s; } c; c.h = (_Float16)f; return c.s;
}

// ---------------- K1: fused setup (scatter | convert | prep_b) ----------------

__global__ __launch_bounds__(256) void setup_fused(
    const int* __restrict__ src, const int* __restrict__ dst,
    int* __restrict__ bucketCursor, unsigned* __restrict__ bucketData,
    const float* __restrict__ x, unsigned* __restrict__ xb, unsigned* __restrict__ xq,
    const float* __restrict__ Wl1, const float* __restrict__ Wr1,
    const float* __restrict__ Wl2, const float* __restrict__ Wr2,
    unsigned short* __restrict__ B1, unsigned short* __restrict__ B2)
{
    __shared__ int cnt[NB_BUCKETS];
    __shared__ int base[NB_BUCKETS];
    int bid = blockIdx.x;
    int t = threadIdx.x;

    if (bid < NBLK_SCATTER) {
        // register-cached edges; rank captured in pass 1 (single LDS-atomic pass)
        for (int i = t; i < NB_BUCKETS; i += 256) cnt[i] = 0;
        __syncthreads();
        int start = bid * EPB;
        int dloc[EPT], sv[EPT], rk[EPT];
#pragma unroll
        for (int j = 0; j < EPT; ++j) {
            int i = start + j * 256 + t;
            dloc[j] = -1;
            if (i < N_EDGES) {
                int d = dst[i];
                dloc[j] = d;
                sv[j] = src[i];
                rk[j] = atomicAdd(&cnt[d >> BUCKET_SHIFT], 1);
            }
        }
        __syncthreads();
        for (int i = t; i < NB_BUCKETS; i += 256) {
            int c = cnt[i];
            base[i] = (c > 0) ? atomicAdd(&bucketCursor[i], c) : 0;
        }
        __syncthreads();
#pragma unroll
        for (int j = 0; j < EPT; ++j) {
            if (dloc[j] >= 0) {
                int b = dloc[j] >> BUCKET_SHIFT;
                int pos = base[b] + rk[j];
                if (pos < BUCKET_CAP)
                    bucketData[(size_t)b * BUCKET_CAP + pos] =
                        ((unsigned)(dloc[j] & 255) << 17) | (unsigned)sv[j];
            }
        }
    } else if (bid < NBLK_SCATTER + NBLK_CONVERT) {
        // 2 float4s per thread; uint4 write to xb, uint2 write to xq
        long long g = (long long)(bid - NBLK_SCATTER) * 256 + t;
        if (g < (long long)N_NODES * 16) {
            float4 v0 = ((const float4*)x)[g * 2];
            float4 v1 = ((const float4*)x)[g * 2 + 1];
            uint4 ob;
            ob.x = (unsigned)f2bf(v0.x) | ((unsigned)f2bf(v0.y) << 16);
            ob.y = (unsigned)f2bf(v0.z) | ((unsigned)f2bf(v0.w) << 16);
            ob.z = (unsigned)f2bf(v1.x) | ((unsigned)f2bf(v1.y) << 16);
            ob.w = (unsigned)f2bf(v1.z) | ((unsigned)f2bf(v1.w) << 16);
            ((uint4*)xb)[g] = ob;
            int q0 = 0, q1 = 0;
            q0 = __builtin_amdgcn_cvt_pk_fp8_f32(v0.x, v0.y, q0, false);
            q0 = __builtin_amdgcn_cvt_pk_fp8_f32(v0.z, v0.w, q0, true);
            q1 = __builtin_amdgcn_cvt_pk_fp8_f32(v1.x, v1.y, q1, false);
            q1 = __builtin_amdgcn_cvt_pk_fp8_f32(v1.z, v1.w, q1, true);
            ((uint2*)xq)[g] = make_uint2((unsigned)q0, (unsigned)q1);
        }
    } else {
        int e = (bid - NBLK_SCATTER - NBLK_CONVERT) * 256 + t;
        if (e < 256 * 128) {
            int k = e >> 7, n = e & 127;
            float w = (k < 128) ? Wl1[k * 128 + n] : Wr1[(k - 128) * 128 + n];
            int kstep = k >> 5, quad = (k >> 3) & 3, j = k & 7;
            int lane = quad * 16 + (n & 15), ntile = n >> 4;
            B1[((kstep * 8 + ntile) * 64 + lane) * 8 + j] = f2bf(w);
        } else if (e < 256 * 128 + 128 * 128) {
            int e2 = e - 256 * 128;
            int k = e2 >> 7, n = e2 & 127;
            float w = (n < 64) ? Wl2[k * 64 + n] : Wr2[k * 64 + (n - 64)];
            int kstep = k >> 5, quad = (k >> 3) & 3, j = k & 7;
            int lane = quad * 16 + (n & 15), ntile = n >> 4;
            B2[((kstep * 8 + ntile) * 64 + lane) * 8 + j] = f2bf(w);
        }
    }
}

// ---------------- K2: bucket -> CSR (self-scanning) ----------------

__global__ __launch_bounds__(256) void bucket_to_csr(
    const unsigned* __restrict__ bucketData, const int* __restrict__ bucketCursor,
    int* __restrict__ rowStart, int* __restrict__ srcSorted)
{
    __shared__ unsigned ent[BUCKET_CAP];
    __shared__ int hcnt[256];
    __shared__ int excl[256];
    __shared__ int ss[256];
    __shared__ int red[256];
    int b = blockIdx.x;
    int t = threadIdx.x;

    int partial = 0;
    for (int i = t; i < NB_BUCKETS; i += 256) {
        int c = bucketCursor[i];
        if (i < b) partial += c;
    }
    red[t] = partial;
    __syncthreads();
    for (int off = 128; off > 0; off >>= 1) {
        if (t < off) red[t] += red[t + off];
        __syncthreads();
    }
    int gbase = red[0];
    int n = bucketCursor[b];
    if (b == NB_BUCKETS - 1 && t == 0) rowStart[N_NODES] = gbase + n;
    if (n > BUCKET_CAP) n = BUCKET_CAP;

    hcnt[t] = 0;
    __syncthreads();
    for (int i = t; i < n; i += 256) {
        unsigned v = bucketData[(size_t)b * BUCKET_CAP + i];
        ent[i] = v;
        atomicAdd(&hcnt[v >> 17], 1);
    }
    __syncthreads();
    int myc = hcnt[t];
    ss[t] = myc;
    __syncthreads();
    for (int off = 1; off < 256; off <<= 1) {
        int tmp = (t >= off) ? ss[t - off] : 0;
        __syncthreads();
        ss[t] += tmp;
        __syncthreads();
    }
    excl[t] = ss[t] - myc;
    int node = b * 256 + t;
    if (node < N_NODES) rowStart[node] = gbase + excl[t];
    hcnt[t] = 0;
    __syncthreads();
    for (int i = t; i < n; i += 256) {
        unsigned v = ent[i];
        int d = v >> 17;
        int r = atomicAdd(&hcnt[d], 1);
        srcSorted[gbase + excl[d] + r] = (int)(v & 0x1FFFF);
    }
}

// ---------------- K3: agg1 (fp8 gather, 8 lanes/edge uint4, 16 edges/iter) ----------------

__global__ void agg1_kernel(const unsigned* __restrict__ xq, const int* __restrict__ rowStart,
                            const int* __restrict__ srcSorted, unsigned* __restrict__ meanb) {
    int wave = threadIdx.x >> 6;
    int lane = threadIdx.x & 63;
    int node = blockIdx.x * 4 + wave;
    if (node >= N_NODES) return;
    int b = rowStart[node], e = rowStart[node + 1];
    int g  = lane >> 3;    // edge group 0..7
    int lf = lane & 7;     // uint4 index in row; features 16lf..16lf+15
    float a[16];
#pragma unroll
    for (int k = 0; k < 16; ++k) a[k] = 0.f;
    int i = b;
    for (; i + 16 <= e; i += 16) {
        int sA = srcSorted[i + g];
        int sB = srcSorted[i + 8 + g];
        uint4 uA = ((const uint4*)(xq + (size_t)sA * 32))[lf];
        uint4 uB = ((const uint4*)(xq + (size_t)sB * 32))[lf];
        f32x2 v;
        v = __builtin_amdgcn_cvt_pk_f32_fp8(uA.x, false); a[0] += v.x;  a[1] += v.y;
        v = __builtin_amdgcn_cvt_pk_f32_fp8(uA.x, true);  a[2] += v.x;  a[3] += v.y;
        v = __builtin_amdgcn_cvt_pk_f32_fp8(uA.y, false); a[4] += v.x;  a[5] += v.y;
        v = __builtin_amdgcn_cvt_pk_f32_fp8(uA.y, true);  a[6] += v.x;  a[7] += v.y;
        v = __builtin_amdgcn_cvt_pk_f32_fp8(uA.z, false); a[8] += v.x;  a[9] += v.y;
        v = __builtin_amdgcn_cvt_pk_f32_fp8(uA.z, true);  a[10] += v.x; a[11] += v.y;
        v = __builtin_amdgcn_cvt_pk_f32_fp8(uA.w, false); a[12] += v.x; a[13] += v.y;
        v = __builtin_amdgcn_cvt_pk_f32_fp8(uA.w, true);  a[14] += v.x; a[15] += v.y;
        v = __builtin_amdgcn_cvt_pk_f32_fp8(uB.x, false); a[0] += v.x;  a[1] += v.y;
        v = __builtin_amdgcn_cvt_pk_f32_fp8(uB.x, true);  a[2] += v.x;  a[3] += v.y;
        v = __builtin_amdgcn_cvt_pk_f32_fp8(uB.y, false); a[4] += v.x;  a[5] += v.y;
        v = __builtin_amdgcn_cvt_pk_f32_fp8(uB.y, true);  a[6] += v.x;  a[7] += v.y;
        v = __builtin_amdgcn_cvt_pk_f32_fp8(uB.z, false); a[8] += v.x;  a[9] += v.y;
        v = __builtin_amdgcn_cvt_pk_f32_fp8(uB.z, true);  a[10] += v.x; a[11] += v.y;
        v = __builtin_amdgcn_cvt_pk_f32_fp8(uB.w, false); a[12] += v.x; a[13] += v.y;
        v = __builtin_amdgcn_cvt_pk_f32_fp8(uB.w, true);  a[14] += v.x; a[15] += v.y;
    }
    for (; i < e; i += 8) {
        int idx = i + g;
        bool valid = idx < e;
        int s = srcSorted[valid ? idx : i];
        uint4 u = ((const uint4*)(xq + (size_t)s * 32))[lf];
        float w = valid ? 1.f : 0.f;
        f32x2 v;
        v = __builtin_amdgcn_cvt_pk_f32_fp8(u.x, false); a[0] = fmaf(v.x, w, a[0]);   a[1] = fmaf(v.y, w, a[1]);
        v = __builtin_amdgcn_cvt_pk_f32_fp8(u.x, true);  a[2] = fmaf(v.x, w, a[2]);   a[3] = fmaf(v.y, w, a[3]);
        v = __builtin_amdgcn_cvt_pk_f32_fp8(u.y, false); a[4] = fmaf(v.x, w, a[4]);   a[5] = fmaf(v.y, w, a[5]);
        v = __builtin_amdgcn_cvt_pk_f32_fp8(u.y, true);  a[6] = fmaf(v.x, w, a[6]);   a[7] = fmaf(v.y, w, a[7]);
        v = __builtin_amdgcn_cvt_pk_f32_fp8(u.z, false); a[8] = fmaf(v.x, w, a[8]);   a[9] = fmaf(v.y, w, a[9]);
        v = __builtin_amdgcn_cvt_pk_f32_fp8(u.z, true);  a[10] = fmaf(v.x, w, a[10]); a[11] = fmaf(v.y, w, a[11]);
        v = __builtin_amdgcn_cvt_pk_f32_fp8(u.w, false); a[12] = fmaf(v.x, w, a[12]); a[13] = fmaf(v.y, w, a[13]);
        v = __builtin_amdgcn_cvt_pk_f32_fp8(u.w, true);  a[14] = fmaf(v.x, w, a[14]); a[15] = fmaf(v.y, w, a[15]);
    }
#pragma unroll
    for (int k = 0; k < 16; ++k) a[k] += __shfl_down(a[k], 32);
#pragma unroll
    for (int k = 0; k < 16; ++k) a[k] += __shfl_down(a[k], 16);
#pragma unroll
    for (int k = 0; k < 16; ++k) a[k] += __shfl_down(a[k], 8);
    if (lane < 8) {
        float inv = 1.0f / (float)max(e - b, 1);
        uint4 o0, o1;
        o0.x = (unsigned)f2bf(a[0] * inv)  | ((unsigned)f2bf(a[1] * inv) << 16);
        o0.y = (unsigned)f2bf(a[2] * inv)  | ((unsigned)f2bf(a[3] * inv) << 16);
        o0.z = (unsigned)f2bf(a[4] * inv)  | ((unsigned)f2bf(a[5] * inv) << 16);
        o0.w = (unsigned)f2bf(a[6] * inv)  | ((unsigned)f2bf(a[7] * inv) << 16);
        o1.x = (unsigned)f2bf(a[8] * inv)  | ((unsigned)f2bf(a[9] * inv) << 16);
        o1.y = (unsigned)f2bf(a[10] * inv) | ((unsigned)f2bf(a[11] * inv) << 16);
        o1.z = (unsigned)f2bf(a[12] * inv) | ((unsigned)f2bf(a[13] * inv) << 16);
        o1.w = (unsigned)f2bf(a[14] * inv) | ((unsigned)f2bf(a[15] * inv) << 16);
        ((uint4*)(meanb + (size_t)node * 64))[lf * 2]     = o0;
        ((uint4*)(meanb + (size_t)node * 64))[lf * 2 + 1] = o1;
    }
}

// ---------------- K4: fused GEMM, 512 thr, 32 KB B ping-buffer (3 phases) ----------------
#define HSTRIDE 136   // shorts; 272 B rows (16B aligned), 2-way bank alias only

__global__ __launch_bounds__(512) void gemm12_kernel(
    const unsigned short* __restrict__ meanb, const unsigned short* __restrict__ xb,
    const unsigned short* __restrict__ B1f, const unsigned short* __restrict__ B2f,
    const float* __restrict__ bl1, const float* __restrict__ bl2,
    unsigned short* __restrict__ p, float* __restrict__ q)
{
    __shared__ unsigned short hTile[128 * HSTRIDE];   // 34,816 B
    __shared__ int ldsB[8192];                        // 32,768 B ping buffer
    int tid = threadIdx.x;
    int lane = tid & 63;
    int waveId = tid >> 6;            // 0..7
    int m = lane & 15, quad = lane >> 4;
    int rowBase = blockIdx.x * 128 + waveId * 16;
    int arow = rowBase + m;
    bool ok = arow < N_NODES;

    // Prefetch all A fragments (in flight during B staging)
    bf16x8 afM[4], afX[4];
#pragma unroll
    for (int ks = 0; ks < 4; ++ks) {
        int kglob = ks * 32 + quad * 8;
        afM[ks] = ok ? *(const bf16x8*)(meanb + (size_t)arow * 128 + kglob) : (bf16x8)(short)0;
        afX[ks] = ok ? *(const bf16x8*)(xb   + (size_t)arow * 128 + kglob) : (bf16x8)(short)0;
    }

    const bf16x8* Bv = (const bf16x8*)ldsB;
    f32x4 acc[8];
#pragma unroll
    for (int t = 0; t < 8; ++t) acc[t] = (f32x4){0.f, 0.f, 0.f, 0.f};

    // ---- phase A: B1 ksteps 0-3 (meanb half) ----
    for (int i = tid; i < 2048; i += 512)
        ((int4*)ldsB)[i] = ((const int4*)B1f)[i];
    __syncthreads();
#pragma unroll
    for (int ks = 0; ks < 4; ++ks)
#pragma unroll
        for (int nt = 0; nt < 8; ++nt)
            acc[nt] = __builtin_amdgcn_mfma_f32_16x16x32_bf16(
                afM[ks], Bv[(ks * 8 + nt) * 64 + lane], acc[nt], 0, 0, 0);
    __syncthreads();

    // ---- phase B: B1 ksteps 4-7 (xb half) ----
    for (int i = tid; i < 2048; i += 512)
        ((int4*)ldsB)[i] = ((const int4*)B1f)[2048 + i];
    __syncthreads();
#pragma unroll
    for (int ks = 0; ks < 4; ++ks)
#pragma unroll
        for (int nt = 0; nt < 8; ++nt)
            acc[nt] = __builtin_amdgcn_mfma_f32_16x16x32_bf16(
                afX[ks], Bv[(ks * 8 + nt) * 64 + lane], acc[nt], 0, 0, 0);
    __syncthreads();   // all waves done reading ldsB before B2 overwrite

    // epilogue 1 -> wave-local hTile rows [waveId*16, waveId*16+16)
#pragma unroll
    for (int nt = 0; nt < 8; ++nt) {
        int col = nt * 16 + m;
        float bias = bl1[col];
#pragma unroll
        for (int r = 0; r < 4; ++r) {
            int rowLocal = waveId * 16 + quad * 4 + r;
            float v = fmaxf(acc[nt][r] + bias, 0.f);
            hTile[rowLocal * HSTRIDE + col] = f2bf(v);
        }
    }

    // ---- phase C: B2 ----
    for (int i = tid; i < 2048; i += 512)
        ((int4*)ldsB)[i] = ((const int4*)B2f)[i];
    __syncthreads();

    f32x4 acc2[8];
#pragma unroll
    for (int t = 0; t < 8; ++t) acc2[t] = (f32x4){0.f, 0.f, 0.f, 0.f};
#pragma unroll
    for (int ks = 0; ks < 4; ++ks) {
        int k0 = ks * 32 + quad * 8;
        bf16x8 af = *(const bf16x8*)&hTile[(waveId * 16 + m) * HSTRIDE + k0];
#pragma unroll
        for (int nt = 0; nt < 8; ++nt)
            acc2[nt] = __builtin_amdgcn_mfma_f32_16x16x32_bf16(
                af, Bv[(ks * 8 + nt) * 64 + lane], acc2[nt], 0, 0, 0);
    }

#pragma unroll
    for (int nt = 0; nt < 8; ++nt) {
        int col = nt * 16 + m;
        float bias = (col >= 64) ? bl2[col - 64] : 0.f;
#pragma unroll
        for (int r = 0; r < 4; ++r) {
            int row = rowBase + quad * 4 + r;
            if (row < N_NODES) {
                float v = acc2[nt][r];
                if (col < 64) {
#if USE_FDOT2
                    p[(size_t)row * 64 + col] = f2h_bits(v);
#else
                    p[(size_t)row * 64 + col] = f2bf(v);
#endif
                } else {
                    q[(size_t)row * 64 + (col - 64)] = v + bias;
                }
            }
        }
    }
}

// ---------------- K5: agg2 (p gather, 8 lanes/edge uint4, 16 edges/iter) ----------------

__global__ void agg2_kernel(const unsigned* __restrict__ p, const float* __restrict__ q,
                            const int* __restrict__ rowStart, const int* __restrict__ srcSorted,
                            float* __restrict__ out) {
    int wave = threadIdx.x >> 6;
    int lane = threadIdx.x & 63;
    int node = blockIdx.x * 4 + wave;
    if (node >= N_NODES) return;
    int b = rowStart[node], e = rowStart[node + 1];
    int g  = lane >> 3;    // edge group 0..7
    int lf = lane & 7;     // uint4 index in row; features 8lf..8lf+7
    float a0=0.f,a1=0.f,a2=0.f,a3=0.f,a4=0.f,a5=0.f,a6=0.f,a7=0.f;
#if USE_FDOT2
    const h2 ONE0 = {(_Float16)1.0f, (_Float16)0.0f};
    const h2 ONE1 = {(_Float16)0.0f, (_Float16)1.0f};
#endif
    int i = b;
    for (; i + 16 <= e; i += 16) {
        int sA = srcSorted[i + g];
        int sB = srcSorted[i + 8 + g];
        uint4 uA = ((const uint4*)(p + (size_t)sA * 32))[lf];
        uint4 uB = ((const uint4*)(p + (size_t)sB * 32))[lf];
#if USE_FDOT2
        a0 = __builtin_amdgcn_fdot2(as_h2(uA.x), ONE0, a0, false);
        a1 = __builtin_amdgcn_fdot2(as_h2(uA.x), ONE1, a1, false);
        a2 = __builtin_amdgcn_fdot2(as_h2(uA.y), ONE0, a2, false);
        a3 = __builtin_amdgcn_fdot2(as_h2(uA.y), ONE1, a3, false);
        a4 = __builtin_amdgcn_fdot2(as_h2(uA.z), ONE0, a4, false);
        a5 = __builtin_amdgcn_fdot2(as_h2(uA.z), ONE1, a5, false);
        a6 = __builtin_amdgcn_fdot2(as_h2(uA.w), ONE0, a6, false);
        a7 = __builtin_amdgcn_fdot2(as_h2(uA.w), ONE1, a7, false);
        a0 = __builtin_amdgcn_fdot2(as_h2(uB.x), ONE0, a0, false);
        a1 = __builtin_amdgcn_fdot2(as_h2(uB.x), ONE1, a1, false);
        a2 = __builtin_amdgcn_fdot2(as_h2(uB.y), ONE0, a2, false);
        a3 = __builtin_amdgcn_fdot2(as_h2(uB.y), ONE1, a3, false);
        a4 = __builtin_amdgcn_fdot2(as_h2(uB.z), ONE0, a4, false);
        a5 = __builtin_amdgcn_fdot2(as_h2(uB.z), ONE1, a5, false);
        a6 = __builtin_amdgcn_fdot2(as_h2(uB.w), ONE0, a6, false);
        a7 = __builtin_amdgcn_fdot2(as_h2(uB.w), ONE1, a7, false);
#else
        a0 += bf2f_lo(uA.x) + bf2f_lo(uB.x);
        a1 += bf2f_hi(uA.x) + bf2f_hi(uB.x);
        a2 += bf2f_lo(uA.y) + bf2f_lo(uB.y);
        a3 += bf2f_hi(uA.y) + bf2f_hi(uB.y);
        a4 += bf2f_lo(uA.z) + bf2f_lo(uB.z);
        a5 += bf2f_hi(uA.z) + bf2f_hi(uB.z);
        a6 += bf2f_lo(uA.w) + bf2f_lo(uB.w);
        a7 += bf2f_hi(uA.w) + bf2f_hi(uB.w);
#endif
    }
    for (; i < e; i += 8) {
        int idx = i + g;
        bool valid = idx < e;
        int s = srcSorted[valid ? idx : i];
        uint4 u = ((const uint4*)(p + (size_t)s * 32))[lf];
        float w = valid ? 1.f : 0.f;
#if USE_FDOT2
        h2 wv0 = {(_Float16)w, (_Float16)0.0f};
        h2 wv1 = {(_Float16)0.0f, (_Float16)w};
        a0 = __builtin_amdgcn_fdot2(as_h2(u.x), wv0, a0, false);
        a1 = __builtin_amdgcn_fdot2(as_h2(u.x), wv1, a1, false);
        a2 = __builtin_amdgcn_fdot2(as_h2(u.y), wv0, a2, false);
        a3 = __builtin_amdgcn_fdot2(as_h2(u.y), wv1, a3, false);
        a4 = __builtin_amdgcn_fdot2(as_h2(u.z), wv0, a4, false);
        a5 = __builtin_amdgcn_fdot2(as_h2(u.z), wv1, a5, false);
        a6 = __builtin_amdgcn_fdot2(as_h2(u.w), wv0, a6, false);
        a7 = __builtin_amdgcn_fdot2(as_h2(u.w), wv1, a7, false);
#else
        a0 = fmaf(bf2f_lo(u.x), w, a0);
        a1 = fmaf(bf2f_hi(u.x), w, a1);
        a2 = fmaf(bf2f_lo(u.y), w, a2);
        a3 = fmaf(bf2f_hi(u.y), w, a3);
        a4 = fmaf(bf2f_lo(u.z), w, a4);
        a5 = fmaf(bf2f_hi(u.z), w, a5);
        a6 = fmaf(bf2f_lo(u.w), w, a6);
        a7 = fmaf(bf2f_hi(u.w), w, a7);
#endif
    }
    a0 += __shfl_down(a0, 32); a1 += __shfl_down(a1, 32);
    a2 += __shfl_down(a2, 32); a3 += __shfl_down(a3, 32);
    a4 += __shfl_down(a4, 32); a5 += __shfl_down(a5, 32);
    a6 += __shfl_down(a6, 32); a7 += __shfl_down(a7, 32);
    a0 += __shfl_down(a0, 16); a1 += __shfl_down(a1, 16);
    a2 += __shfl_down(a2, 16); a3 += __shfl_down(a3, 16);
    a4 += __shfl_down(a4, 16); a5 += __shfl_down(a5, 16);
    a6 += __shfl_down(a6, 16); a7 += __shfl_down(a7, 16);
    a0 += __shfl_down(a0, 8);  a1 += __shfl_down(a1, 8);
    a2 += __shfl_down(a2, 8);  a3 += __shfl_down(a3, 8);
    a4 += __shfl_down(a4, 8);  a5 += __shfl_down(a5, 8);
    a6 += __shfl_down(a6, 8);  a7 += __shfl_down(a7, 8);
    if (lane < 8) {
        float inv = 1.0f / (float)max(e - b, 1);
        f32x4 qv0 = ((const f32x4*)(q + (size_t)node * 64))[lf * 2];
        f32x4 qv1 = ((const f32x4*)(q + (size_t)node * 64))[lf * 2 + 1];
        f32x4 o0, o1;
        o0.x = 1.0f / (1.0f + __expf(-(a0 * inv + qv0.x)));
        o0.y = 1.0f / (1.0f + __expf(-(a1 * inv + qv0.y)));
        o0.z = 1.0f / (1.0f + __expf(-(a2 * inv + qv0.z)));
        o0.w = 1.0f / (1.0f + __expf(-(a3 * inv + qv0.w)));
        o1.x = 1.0f / (1.0f + __expf(-(a4 * inv + qv1.x)));
        o1.y = 1.0f / (1.0f + __expf(-(a5 * inv + qv1.y)));
        o1.z = 1.0f / (1.0f + __expf(-(a6 * inv + qv1.z)));
        o1.w = 1.0f / (1.0f + __expf(-(a7 * inv + qv1.w)));
        ((f32x4*)(out + (size_t)node * 64))[lf * 2]     = o0;
        ((f32x4*)(out + (size_t)node * 64))[lf * 2 + 1] = o1;
    }
}

// ---------------- launch ----------------

extern "C" void kernel_launch(void* const* d_in, const int* in_sizes, int n_in,
                              void* d_out, int out_size, void* d_ws, size_t ws_size,
                              hipStream_t stream) {
    const float* x   = (const float*)d_in[0];
    const int*   ei  = (const int*)d_in[1];
    const float* Wl1 = (const float*)d_in[2];
    const float* bl1 = (const float*)d_in[3];
    const float* Wr1 = (const float*)d_in[4];
    const float* Wl2 = (const float*)d_in[5];
    const float* bl2 = (const float*)d_in[6];
    const float* Wr2 = (const float*)d_in[7];
    float* out = (float*)d_out;

    const int* src = ei;
    const int* dst = ei + N_EDGES;

    char* ws = (char*)d_ws;
    size_t off = 0;
    auto carve = [&](size_t bytes) -> void* {
        void* ptr = ws + off;
        off = (off + bytes + 255) & ~(size_t)255;
        return ptr;
    };
    int* rowStart     = (int*)carve((N_NODES + 1) * sizeof(int));
    int* bucketCursor = (int*)carve(NB_BUCKETS * sizeof(int));
    unsigned* bucketData = (unsigned*)carve((size_t)NB_BUCKETS * BUCKET_CAP * sizeof(unsigned));
    int* srcSorted    = (int*)carve(N_EDGES * sizeof(int));
    unsigned* xb      = (unsigned*)carve((size_t)N_NODES * 64 * sizeof(unsigned));   // bf16 x
    unsigned* xq      = (unsigned*)carve((size_t)N_NODES * 32 * sizeof(unsigned));   // fp8 x
    unsigned* meanb   = (unsigned*)carve((size_t)N_NODES * 64 * sizeof(unsigned));
    unsigned short* p = (unsigned short*)carve((size_t)N_NODES * 64 * sizeof(short)); // fp16/bf16
    unsigned short* B1 = (unsigned short*)carve(256 * 128 * sizeof(short));
    unsigned short* B2 = (unsigned short*)carve(128 * 128 * sizeof(short));
    float* q = (float*)xb;   // overlay: q[row] replaces xb[row] after that wave's xb prefetch

    // K1: fused setup
    hipMemsetAsync(bucketCursor, 0, NB_BUCKETS * sizeof(int), stream);
    setup_fused<<<NBLK_SCATTER + NBLK_CONVERT + NBLK_PREPB, 256, 0, stream>>>(
        src, dst, bucketCursor, bucketData, x, xb, xq, Wl1, Wr1, Wl2, Wr2, B1, B2);

    // K2: CSR
    bucket_to_csr<<<NB_BUCKETS, 256, 0, stream>>>(bucketData, bucketCursor, rowStart, srcSorted);

    // K3: layer-1 aggregation
    agg1_kernel<<<(N_NODES + 3) / 4, 256, 0, stream>>>(xq, rowStart, srcSorted, meanb);

    // K4: fused GEMMs (32 KB B ping-buffer, h in LDS)
    gemm12_kernel<<<(N_NODES + 127) / 128, 512, 0, stream>>>(
        (const unsigned short*)meanb, (const unsigned short*)xb, B1, B2, bl1, bl2, p, q);

    // K5: layer-2 aggregation + sigmoid
    agg2_kernel<<<(N_NODES + 3) / 4, 256, 0, stream>>>((const unsigned*)p, q,
                                                       rowStart, srcSorted, out);
}